// Round 3
// baseline (272.321 us; speedup 1.0000x reference)
//
#include <hip/hip_runtime.h>
#include <hip/hip_bf16.h>

typedef __hip_bfloat16 bf16;
typedef __attribute__((ext_vector_type(8))) short bf16x8;
typedef __attribute__((ext_vector_type(4))) short s16x4;
typedef __attribute__((ext_vector_type(4))) float f32x4;

#define NNODE 512   // B*N

__device__ __forceinline__ float b2f(bf16 v){ return __bfloat162float(v); }
__device__ __forceinline__ float siluf(float x){ return x / (1.f + __expf(-x)); }
__device__ __forceinline__ float tanhfast(float x){ return 1.f - 2.f/(__expf(2.f*x)+1.f); }
__device__ __forceinline__ float celu2(float x){ return x > 0.f ? x : 2.f*(__expf(0.5f*x)-1.f); }
__device__ __forceinline__ float bs2f(short v){ union{unsigned int i; float f;} t; t.i = ((unsigned int)(unsigned short)v) << 16; return t.f; }
__device__ __forceinline__ short f2bs(float x){ union{ bf16 b; short s; } u; u.b = __float2bfloat16(x); return u.s; }
__device__ __forceinline__ float lo16f(unsigned int u){ union{unsigned int i; float f;} t; t.i = u<<16; return t.f; }
__device__ __forceinline__ float hi16f(unsigned int u){ union{unsigned int i; float f;} t; t.i = u & 0xffff0000u; return t.f; }

// ---- dtype-polymorphic scalar load/store -------------------------------------------
template<typename T> __device__ __forceinline__ float ldv(const void* p, int i);
template<> __device__ __forceinline__ float ldv<float>(const void* p, int i){ return ((const float*)p)[i]; }
template<> __device__ __forceinline__ float ldv<bf16 >(const void* p, int i){ return b2f(((const bf16*)p)[i]); }

template<typename T> __device__ __forceinline__ void stv(void* p, int i, float v);
template<> __device__ __forceinline__ void stv<float>(void* p, int i, float v){ ((float*)p)[i] = v; }
template<> __device__ __forceinline__ void stv<bf16 >(void* p, int i, float v){ ((bf16*)p)[i] = __float2bfloat16(v); }

template<typename T> __device__ __forceinline__ short ldbs(const void* p, int i);
template<> __device__ __forceinline__ short ldbs<bf16 >(const void* p, int i){ union{ bf16 b; short s; } u; u.b = ((const bf16*)p)[i]; return u.s; }
template<> __device__ __forceinline__ short ldbs<float>(const void* p, int i){ return f2bs(((const float*)p)[i]); }

struct Args {
    const void *h,*x,*v,*Win,*bin,*means,*betas,*Wo1,*bo1,*Wo2,*bo2,*Wsem,*bsem,*Wx,
               *Wp1,*bp1,*Wp2,*bp2,*Wn1,*bn1,*Wn2,*bn2,*Wv1,*bv1,*Wv2,*Wvm;
};

__device__ __forceinline__ bool detect_f32(const void* means){
    float v = b2f(((const bf16*)means)[0]);
    return (fabsf(v) > 1.0f || v != v);
}

// ---- per-node precompute -----------------------------------------------------------
// wxtE layout [h][384][64]: n<256 -> Wx transposed; n in [256,320) -> Wn1-mid bf16 HI;
// n in [320,384) -> Wn1-mid bf16 LO (residual).  hi+lo keeps the h_e@Wn1 fold at ~f32
// precision so the MFMA fold cannot move absmax.
template<typename T>
__device__ __forceinline__ void nodepre_body(const Args& A, short* __restrict__ U1,
                                             float* __restrict__ Aj, short* __restrict__ WxT,
                                             float* sh, float (*p1)[64], float (*p2)[64])
{
    int bn = blockIdx.x, tid = threadIdx.x;
    int t = tid & 63, ks = tid >> 6;
    if (tid < 64) sh[tid] = ldv<T>(A.h, bn*64 + tid);
    __syncthreads();
    float a1 = 0.f;
    #pragma unroll
    for (int q = 0; q < 16; ++q){
        int f = ks*16 + q;
        a1 += sh[f] * ldv<T>(A.Wo1, f*64 + t);
    }
    p1[ks][t] = a1;
    if (t < 50){
        float a2 = 0.f;
        #pragma unroll
        for (int q = 0; q < 16; ++q){
            int f = ks*16 + q;
            a2 += sh[f] * ldv<T>(A.Win, f*50 + t);
        }
        p2[ks][t] = a2;
    }
    if (tid < 192){
        int oo = bn*192 + tid;               // [0, 98304)
        int hh = oo / 24576;                 // 24576 = 384*64
        int rem = oo - hh*24576;
        int n = rem >> 6, k = rem & 63;
        short v;
        if (n < 256){
            v = ldbs<T>(A.Wx, (4*k + hh)*256 + n);
        } else if (n < 320){
            v = ldbs<T>(A.Wn1, (64 + 4*k + hh)*64 + (n - 256));
        } else {
            float wv = ldv<T>(A.Wn1, (64 + 4*k + hh)*64 + (n - 320));
            v = f2bs(wv - bs2f(f2bs(wv)));
        }
        WxT[oo] = v;
    }
    __syncthreads();
    if (tid < 64){
        U1[bn*64 + tid] = f2bs(p1[0][tid] + p1[1][tid] + p1[2][tid] + p1[3][tid]);
        float av = (tid < 50) ? (p2[0][tid] + p2[1][tid] + p2[2][tid] + p2[3][tid]) : 0.f;
        Aj[bn*64 + tid] = av;
    }
}

__global__ void __launch_bounds__(256) k_nodepre(Args A, short* __restrict__ U1,
                                                 float* __restrict__ Aj, short* __restrict__ WxT)
{
    __shared__ float sh[64];
    __shared__ float p1[4][64];
    __shared__ float p2[4][64];
    if (detect_f32(A.means)) nodepre_body<float>(A, U1, Aj, WxT, sh, p1, p2);
    else                     nodepre_body<bf16 >(A, U1, Aj, WxT, sh, p1, p2);
}

// ---- fused SAKE layer: one block per node, 512 threads (8 waves) ------------------
// R3: phase-chain collapse. logits fused into edge (same-wave e rows, no barrier);
// att lives in e-row padding (free LDS); h_e phase deleted (folded into xmix as 4
// hi/lo he-tiles); MLP GEMVs split-N with shfl combine (1 barrier each); dv on waves
// 4-7 during cn. Barriers 21 -> 13.
struct SmemPost {
    float red[768];                    // comb_sum                  3072
    float cn[256];                     // comb_norm                 1024
    float fa[64];                      // f1/f3                      256
    float fb[64];                      // f2/f4                      256
    float hep[8][16];                  // he-fold partials           512
    float tmp[8][4];                   // softmax max/sum, dv        128
    float tmp2[8];                     // vscale partials             32
};
struct SmemEdge {
    __align__(16) short wo1t[64*72];   // Wo1r^T [n][k pad72]       9216
    __align__(16) short wo2t[64*72];   // Wo2^T  [n][k pad72]       9216
    __align__(16) short mid[8][16][72];// edge o1 scratch          18432
};
struct Smem {
    __align__(16) bf16  e[256][72];    // cols 0..63 e; bytes 128..143 = att[j][4] f32
    __align__(16) float x4[256][4];    // xhat[3], d                 4096
    float hi[64];                      //                             256
    float ub[64];                      // u2 + bo1                    256
    float wl[64];                      // Wo1 dist row                256
    __align__(16) float kc[64][4];     // mu, beta, bin, aiv         1024
    __align__(16) short wsem[256];     //                             512
    union { SmemEdge edge; SmemPost post; } u;  //                  36864
};                                     // total 80128 -> 2 blocks/CU

__device__ __forceinline__ float* attp(Smem& S, int j){
    return (float*)((short*)S.e + j*72 + 64);
}

template<typename T>
__device__ __forceinline__ void sake_body(const Args& A,
        const short* __restrict__ U1w, const float* __restrict__ Ajw,
        const short* __restrict__ wxt, void* __restrict__ out, Smem& S)
{
    int bi = blockIdx.x;
    int b = bi >> 8, i = bi & 255;
    int tid = threadIdx.x, w = tid >> 6, lane = tid & 63;
    int lane15 = lane & 15, quad = lane >> 4;

    // ---- stage (single phase; u2/aiv read h from GLOBAL to avoid 2nd barrier) -----
    if (tid < 64)  S.hi[tid]   = ldv<T>(A.h, bi*64 + tid);
    if (tid < 256) S.wsem[tid] = ldbs<T>(A.Wsem, tid);
    if (tid < 64){
        bool kv = tid < 50;
        S.kc[tid][0] = kv ? ldv<T>(A.means, tid) : 0.f;
        S.kc[tid][1] = kv ? ldv<T>(A.betas, tid) : 0.f;
        S.kc[tid][2] = kv ? ldv<T>(A.bin,   tid) : 0.f;
        if (!kv) S.kc[tid][3] = 0.f;          // lanes <50 written by wave 1 below
    }
    #pragma unroll
    for (int q = 0; q < 8; ++q){
        int idx = q*512 + tid;                // 0..4095
        int n = idx >> 6, k = idx & 63;
        S.u.edge.wo2t[n*72 + k] = ldbs<T>(A.Wo2, k*64 + n);
        S.u.edge.wo1t[n*72 + k] = (k < 50) ? ldbs<T>(A.Wo1, (128+k)*64 + n) : (short)0;
    }
    float xi0 = ldv<T>(A.x, bi*3+0), xi1 = ldv<T>(A.x, bi*3+1), xi2 = ldv<T>(A.x, bi*3+2);
    if (tid < 256){
        int j = tid;
        float dx = ldv<T>(A.x,(b*256+j)*3+0) - xi0;
        float dy = ldv<T>(A.x,(b*256+j)*3+1) - xi1;
        float dz = ldv<T>(A.x,(b*256+j)*3+2) - xi2;
        float dd = sqrtf(dx*dx + dy*dy + dz*dz + 1e-5f);
        float inv = 1.f/(dd + 1e-5f);
        S.x4[j][0] = dx*inv; S.x4[j][1] = dy*inv; S.x4[j][2] = dz*inv; S.x4[j][3] = dd;
    }
    if (w == 0){
        float u2v = 0.f;
        for (int f = 0; f < 64; ++f) u2v += ldv<T>(A.h, bi*64 + f) * ldv<T>(A.Wo1, (64+f)*64 + lane);
        S.ub[lane] = u2v + ldv<T>(A.bo1, lane);
        S.wl[lane] = ldv<T>(A.Wo1, 178*64 + lane);
    } else if (w == 1 && lane < 50){
        float av = 0.f;
        for (int f = 0; f < 64; ++f) av += ldv<T>(A.h, bi*64 + f) * ldv<T>(A.Win, (64+f)*50 + lane);
        S.kc[lane][3] = av;
    }
    __syncthreads();   // everything staged

    // per-lane hoisted C-init constants: rows m = nf*16 + quad*4 + r
    float ubr[16], wlr[16], bo2r[16];
    #pragma unroll
    for (int nf = 0; nf < 4; ++nf){
        #pragma unroll
        for (int r = 0; r < 4; ++r){
            int m = nf*16 + quad*4 + r;
            ubr[nf*4+r]  = S.ub[m];
            wlr[nf*4+r]  = S.wl[m];
            bo2r[nf*4+r] = ldv<T>(A.bo2, m);
        }
    }

    // ================= edge phase: 2 passes x (8 waves x 16 pairs) =================
    #pragma unroll
    for (int pass = 0; pass < 2; ++pass){
        int j = pass*128 + w*16 + lane15;     // this lane's pair
        float dd  = S.x4[j][3];
        float cut = (dd < 5.f) ? 0.5f*(__cosf(dd*0.6283185307f) + 1.f) : 0.f;
        float ed  = __expf(-dd);
        const float* ajp = Ajw + (b*256 + j)*64;
        bf16x8 Brb[2];
        #pragma unroll
        for (int s = 0; s < 2; ++s){
            int kb = s*32 + quad*8;
            f32x4 a0 = *(const f32x4*)(ajp + kb);
            f32x4 a1 = *(const f32x4*)(ajp + kb + 4);
            bf16x8 bv;
            #pragma unroll
            for (int i2 = 0; i2 < 8; ++i2){
                int k = kb + i2;
                f32x4 kcv = *(const f32x4*)&S.kc[k][0];   // mu, beta, bin, aiv
                float aj = (i2 < 4) ? a0[i2] : a1[i2-4];
                float h1 = aj + kcv[3] + kcv[2];
                float ex = ed - kcv[0];
                float val = cut * __expf(-kcv[1]*ex*ex) * h1;
                bv[i2] = (k < 50) ? f2bs(val) : (short)0;
            }
            Brb[s] = bv;
        }
        const short* u1p = U1w + (b*256 + j)*64;
        #pragma unroll
        for (int nf = 0; nf < 4; ++nf){
            const short* wp = S.u.edge.wo1t + (nf*16 + lane15)*72;
            bf16x8 A0 = *(const bf16x8*)(wp + quad*8);
            bf16x8 A1 = *(const bf16x8*)(wp + 32 + quad*8);
            s16x4 u4 = *(const s16x4*)(u1p + nf*16 + quad*4);
            f32x4 C;
            #pragma unroll
            for (int r = 0; r < 4; ++r)
                C[r] = bs2f(u4[r]) + ubr[nf*4+r] + dd*wlr[nf*4+r];
            C = __builtin_amdgcn_mfma_f32_16x16x32_bf16(A0, Brb[0], C, 0, 0, 0);
            C = __builtin_amdgcn_mfma_f32_16x16x32_bf16(A1, Brb[1], C, 0, 0, 0);
            s16x4 m4;
            #pragma unroll
            for (int r = 0; r < 4; ++r) m4[r] = f2bs(siluf(C[r]));
            *(s16x4*)&S.u.edge.mid[w][lane15][nf*16 + quad*4] = m4;
        }
        bf16x8 Bm0 = *(const bf16x8*)&S.u.edge.mid[w][lane15][quad*8];
        bf16x8 Bm1 = *(const bf16x8*)&S.u.edge.mid[w][lane15][32 + quad*8];
        #pragma unroll
        for (int nf = 0; nf < 4; ++nf){
            const short* wp = S.u.edge.wo2t + (nf*16 + lane15)*72;
            bf16x8 A0 = *(const bf16x8*)(wp + quad*8);
            bf16x8 A1 = *(const bf16x8*)(wp + 32 + quad*8);
            f32x4 C = (f32x4){bo2r[nf*4+0], bo2r[nf*4+1], bo2r[nf*4+2], bo2r[nf*4+3]};
            C = __builtin_amdgcn_mfma_f32_16x16x32_bf16(A0, Bm0, C, 0, 0, 0);
            C = __builtin_amdgcn_mfma_f32_16x16x32_bf16(A1, Bm1, C, 0, 0, 0);
            s16x4 e4;
            #pragma unroll
            for (int r = 0; r < 4; ++r) e4[r] = f2bs(C[r]);
            *(s16x4*)&((short*)S.e)[j*72 + nf*16 + quad*4] = e4;
        }
    }

    // ===== logits fused into edge (tiles {w, 8+w} = rows THIS wave just wrote) =====
    {
        bf16x8 Bs[2];
        #pragma unroll
        for (int ks = 0; ks < 2; ++ks){
            bf16x8 bv = (bf16x8){0,0,0,0,0,0,0,0};
            if (lane15 < 4){
                #pragma unroll
                for (int i2 = 0; i2 < 8; ++i2)
                    bv[i2] = S.wsem[(ks*32 + quad*8 + i2)*4 + lane15];
            }
            Bs[ks] = bv;
        }
        float bsv = (lane15 < 4) ? ldv<T>(A.bsem, lane15) : 0.f;
        #pragma unroll
        for (int t2 = 0; t2 < 2; ++t2){
            int jt = t2 ? (8 + w) : w;
            const short* ep = (const short*)S.e + (jt*16 + lane15)*72;
            bf16x8 A0 = *(const bf16x8*)(ep + quad*8);
            bf16x8 A1 = *(const bf16x8*)(ep + 32 + quad*8);
            f32x4 C = (f32x4){bsv, bsv, bsv, bsv};
            C = __builtin_amdgcn_mfma_f32_16x16x32_bf16(A0, Bs[0], C, 0, 0, 0);
            C = __builtin_amdgcn_mfma_f32_16x16x32_bf16(A1, Bs[1], C, 0, 0, 0);
            if (lane15 < 4){
                #pragma unroll
                for (int r = 0; r < 4; ++r){
                    int jr = jt*16 + quad*4 + r;
                    float lv = celu2(C[r]);
                    if (jr == i) lv -= 1e5f;
                    attp(S, jr)[lane15] = lv;
                }
            }
        }
    }
    __syncthreads();   // e + logits visible

    // ================= softmax over j (4 heads; shfl + 8-wave combine) =============
    float ex0 = 0.f, ex1 = 0.f, ex2 = 0.f, ex3 = 0.f;
    if (tid < 256){
        f32x4 l = *(const f32x4*)attp(S, tid);
        float m0 = l[0], m1 = l[1], m2 = l[2], m3 = l[3];
        #pragma unroll
        for (int off = 1; off < 64; off <<= 1){
            m0 = fmaxf(m0, __shfl_xor(m0, off)); m1 = fmaxf(m1, __shfl_xor(m1, off));
            m2 = fmaxf(m2, __shfl_xor(m2, off)); m3 = fmaxf(m3, __shfl_xor(m3, off));
        }
        if (lane == 0){
            S.u.post.tmp[w][0] = m0; S.u.post.tmp[w][1] = m1;
            S.u.post.tmp[w][2] = m2; S.u.post.tmp[w][3] = m3;
        }
        ex0 = l[0]; ex1 = l[1]; ex2 = l[2]; ex3 = l[3];
    }
    __syncthreads();
    if (tid < 256){
        float m0 = fmaxf(fmaxf(S.u.post.tmp[0][0], S.u.post.tmp[1][0]), fmaxf(S.u.post.tmp[2][0], S.u.post.tmp[3][0]));
        float m1 = fmaxf(fmaxf(S.u.post.tmp[0][1], S.u.post.tmp[1][1]), fmaxf(S.u.post.tmp[2][1], S.u.post.tmp[3][1]));
        float m2 = fmaxf(fmaxf(S.u.post.tmp[0][2], S.u.post.tmp[1][2]), fmaxf(S.u.post.tmp[2][2], S.u.post.tmp[3][2]));
        float m3 = fmaxf(fmaxf(S.u.post.tmp[0][3], S.u.post.tmp[1][3]), fmaxf(S.u.post.tmp[2][3], S.u.post.tmp[3][3]));
        ex0 = __expf(ex0-m0); ex1 = __expf(ex1-m1); ex2 = __expf(ex2-m2); ex3 = __expf(ex3-m3);
        float s0 = ex0, s1 = ex1, s2 = ex2, s3 = ex3;
        #pragma unroll
        for (int off = 1; off < 64; off <<= 1){
            s0 += __shfl_xor(s0, off); s1 += __shfl_xor(s1, off);
            s2 += __shfl_xor(s2, off); s3 += __shfl_xor(s3, off);
        }
        if (lane == 0){
            S.u.post.tmp[4+w][0] = s0; S.u.post.tmp[4+w][1] = s1;
            S.u.post.tmp[4+w][2] = s2; S.u.post.tmp[4+w][3] = s3;
        }
    }
    __syncthreads();
    if (tid < 256){
        float s0 = S.u.post.tmp[4][0]+S.u.post.tmp[5][0]+S.u.post.tmp[6][0]+S.u.post.tmp[7][0];
        float s1 = S.u.post.tmp[4][1]+S.u.post.tmp[5][1]+S.u.post.tmp[6][1]+S.u.post.tmp[7][1];
        float s2 = S.u.post.tmp[4][2]+S.u.post.tmp[5][2]+S.u.post.tmp[6][2]+S.u.post.tmp[7][2];
        float s3 = S.u.post.tmp[4][3]+S.u.post.tmp[5][3]+S.u.post.tmp[6][3]+S.u.post.tmp[7][3];
        *(f32x4*)attp(S, tid) = (f32x4){ex0/s0, ex1/s1, ex2/s2, ex3/s3};
    }
    __syncthreads();

    // ================= x-mixing: att-factored MFMA (nf2-outer, Bh held) ============
    {
        const short* se_s = (const short*)S.e;   // row stride 72 shorts
        #pragma unroll
        for (int nf2 = 0; nf2 < 2; ++nf2){
            int n = w*32 + nf2*16 + lane15;
            bf16x8 Bh[4][2];
            #pragma unroll
            for (int hh = 0; hh < 4; ++hh){
                const short* bp = wxt + (hh*384 + n)*64 + quad*8;
                Bh[hh][0] = *(const bf16x8*)(bp);
                Bh[hh][1] = *(const bf16x8*)(bp + 32);
            }
            float c0 = 0.f, c1 = 0.f, c2 = 0.f;
            for (int mt = 0; mt < 16; ++mt){
                int jq = mt*16 + quad*4;
                f32x4 att4[4];
                #pragma unroll
                for (int r = 0; r < 4; ++r) att4[r] = *(const f32x4*)attp(S, jq + r);
                bf16x8 Af[2];
                #pragma unroll
                for (int ks = 0; ks < 2; ++ks)
                    Af[ks] = *(const bf16x8*)(se_s + (mt*16 + lane15)*72 + ks*32 + quad*8);
                float Pt[4] = {0.f, 0.f, 0.f, 0.f};
                #pragma unroll
                for (int hh = 0; hh < 4; ++hh){
                    f32x4 Cc = (f32x4){0.f,0.f,0.f,0.f};
                    Cc = __builtin_amdgcn_mfma_f32_16x16x32_bf16(Af[0], Bh[hh][0], Cc, 0, 0, 0);
                    Cc = __builtin_amdgcn_mfma_f32_16x16x32_bf16(Af[1], Bh[hh][1], Cc, 0, 0, 0);
                    #pragma unroll
                    for (int r = 0; r < 4; ++r) Pt[r] += att4[r][hh] * Cc[r];
                }
                #pragma unroll
                for (int r = 0; r < 4; ++r){
                    float cf = tanhfast(Pt[r]);
                    f32x4 xh = *(const f32x4*)&S.x4[jq + r][0];
                    c0 += cf*xh[0]; c1 += cf*xh[1]; c2 += cf*xh[2];
                }
            }
            c0 += __shfl_xor(c0, 16); c0 += __shfl_xor(c0, 32);
            c1 += __shfl_xor(c1, 16); c1 += __shfl_xor(c1, 32);
            c2 += __shfl_xor(c2, 16); c2 += __shfl_xor(c2, 32);
            if (quad == 0){
                S.u.post.red[n*3 + 0] = c0;
                S.u.post.red[n*3 + 1] = c1;
                S.u.post.red[n*3 + 2] = c2;
            }
        }
    }

    // ===== he fold: heW[f] = sum_j sum_h att[j][h] * (e_j @ Wn1mid_h)[f] ===========
    // wave w: he-tile (w>>1) (f in [(w>>1)*16, +16)), mt half (w&1). hi+lo MFMA.
    {
        const short* se_s = (const short*)S.e;
        int t16 = (w >> 1) * 16;
        int mt0 = (w & 1) * 8;
        float heacc = 0.f;
        #pragma unroll
        for (int hh = 0; hh < 4; ++hh){
            const short* bhp = wxt + (hh*384 + 256 + t16 + lane15)*64 + quad*8;
            bf16x8 Bhi0 = *(const bf16x8*)(bhp);
            bf16x8 Bhi1 = *(const bf16x8*)(bhp + 32);
            bf16x8 Blo0 = *(const bf16x8*)(bhp + 4096);
            bf16x8 Blo1 = *(const bf16x8*)(bhp + 4096 + 32);
            for (int mt = mt0; mt < mt0 + 8; ++mt){
                bf16x8 Af0 = *(const bf16x8*)(se_s + (mt*16 + lane15)*72 + quad*8);
                bf16x8 Af1 = *(const bf16x8*)(se_s + (mt*16 + lane15)*72 + 32 + quad*8);
                f32x4 Cc = (f32x4){0.f,0.f,0.f,0.f};
                Cc = __builtin_amdgcn_mfma_f32_16x16x32_bf16(Af0, Bhi0, Cc, 0, 0, 0);
                Cc = __builtin_amdgcn_mfma_f32_16x16x32_bf16(Af1, Bhi1, Cc, 0, 0, 0);
                Cc = __builtin_amdgcn_mfma_f32_16x16x32_bf16(Af0, Blo0, Cc, 0, 0, 0);
                Cc = __builtin_amdgcn_mfma_f32_16x16x32_bf16(Af1, Blo1, Cc, 0, 0, 0);
                #pragma unroll
                for (int r = 0; r < 4; ++r)
                    heacc += attp(S, mt*16 + quad*4 + r)[hh] * Cc[r];
            }
        }
        heacc += __shfl_xor(heacc, 16);
        heacc += __shfl_xor(heacc, 32);
        if (quad == 0) S.u.post.hep[w][lane15] = heacc;
    }
    __syncthreads();

    // ================= cn (waves 0-3) | dv partials (waves 4-7) ====================
    const float sc = 1.f/256.f;
    if (tid < 256){
        float c0 = S.u.post.red[tid*3+0]*sc, c1 = S.u.post.red[tid*3+1]*sc, c2 = S.u.post.red[tid*3+2]*sc;
        S.u.post.cn[tid] = c0*c0 + c1*c1 + c2*c2;
    } else {
        int c = (w-4)*64 + lane;
        float wv = ldv<T>(A.Wvm, c);
        float d0 = S.u.post.red[c*3+0]*sc*wv;
        float d1 = S.u.post.red[c*3+1]*sc*wv;
        float d2 = S.u.post.red[c*3+2]*sc*wv;
        #pragma unroll
        for (int off = 1; off < 64; off <<= 1){
            d0 += __shfl_xor(d0, off); d1 += __shfl_xor(d1, off); d2 += __shfl_xor(d2, off);
        }
        if (lane == 0){ S.u.post.tmp[w-4][0] = d0; S.u.post.tmp[w-4][1] = d1; S.u.post.tmp[w-4][2] = d2; }
    }
    __syncthreads();

    int fs = lane & 7, ks8 = lane >> 3;
    int fo = w*8 + fs;
    // p1: K=256 split 8 ways over lanes
    {
        float acc = 0.f;
        int c0 = ks8*32;
        for (int it = 0; it < 32; ++it){
            int c = c0 + it;
            acc += S.u.post.cn[c] * ldv<T>(A.Wp1, c*64 + fo);
        }
        acc += __shfl_xor(acc, 8); acc += __shfl_xor(acc, 16); acc += __shfl_xor(acc, 32);
        if (lane < 8) S.u.post.fa[w*8 + lane] = siluf(acc + ldv<T>(A.bp1, w*8 + lane));
    }
    __syncthreads();
    // p2: K=64
    {
        float acc = 0.f;
        #pragma unroll
        for (int q = 0; q < 8; ++q){
            int k = ks8*8 + q;
            acc += S.u.post.fa[k] * ldv<T>(A.Wp2, k*64 + fo);
        }
        acc += __shfl_xor(acc, 8); acc += __shfl_xor(acc, 16); acc += __shfl_xor(acc, 32);
        if (lane < 8) S.u.post.fb[w*8 + lane] = siluf(acc + ldv<T>(A.bp2, w*8 + lane));
    }
    __syncthreads();
    // n1: K=128 explicit (h | f2) + heW from fold
    {
        float acc = 0.f;
        #pragma unroll
        for (int q = 0; q < 8; ++q){
            int k = ks8*8 + q;
            acc += S.hi[k]        * ldv<T>(A.Wn1, k*64 + fo);
            acc += S.u.post.fb[k] * ldv<T>(A.Wn1, (320+k)*64 + fo);
        }
        acc += __shfl_xor(acc, 8); acc += __shfl_xor(acc, 16); acc += __shfl_xor(acc, 32);
        if (lane < 8){
            int f = w*8 + lane;
            float heW = S.u.post.hep[2*(f>>4)][f&15] + S.u.post.hep[2*(f>>4)+1][f&15];
            S.u.post.fa[f] = siluf(acc + heW + ldv<T>(A.bn1, f));
        }
    }
    __syncthreads();
    // n2: K=64 -> h_new
    {
        float acc = 0.f;
        #pragma unroll
        for (int q = 0; q < 8; ++q){
            int k = ks8*8 + q;
            acc += S.u.post.fa[k] * ldv<T>(A.Wn2, k*64 + fo);
        }
        acc += __shfl_xor(acc, 8); acc += __shfl_xor(acc, 16); acc += __shfl_xor(acc, 32);
        if (lane < 8){
            int f = w*8 + lane;
            float hn = S.hi[f] + siluf(acc + ldv<T>(A.bn2, f));
            stv<T>(out, bi*64 + f, hn);
            S.u.post.fb[f] = hn;
        }
    }
    __syncthreads();
    // v1: K=64 -> term partials per wave
    {
        float acc = 0.f;
        #pragma unroll
        for (int q = 0; q < 8; ++q){
            int k = ks8*8 + q;
            acc += S.u.post.fb[k] * ldv<T>(A.Wv1, k*64 + fo);
        }
        acc += __shfl_xor(acc, 8); acc += __shfl_xor(acc, 16); acc += __shfl_xor(acc, 32);
        float term = siluf(acc + ldv<T>(A.bv1, fo)) * ldv<T>(A.Wv2, fo);
        term += __shfl_xor(term, 1); term += __shfl_xor(term, 2); term += __shfl_xor(term, 4);
        if (lane == 0) S.u.post.tmp2[w] = term;
    }
    __syncthreads();
    if (tid < 3){
        float t = S.u.post.tmp2[0]+S.u.post.tmp2[1]+S.u.post.tmp2[2]+S.u.post.tmp2[3]
                + S.u.post.tmp2[4]+S.u.post.tmp2[5]+S.u.post.tmp2[6]+S.u.post.tmp2[7];
        float vscale = 2.f / (1.f + __expf(-t));
        float dv = S.u.post.tmp[0][tid] + S.u.post.tmp[1][tid] + S.u.post.tmp[2][tid] + S.u.post.tmp[3][tid];
        float vn = dv + vscale * ldv<T>(A.v, bi*3 + tid);
        float xn = ldv<T>(A.x, bi*3 + tid) + vn;
        stv<T>(out, 32768 + bi*3 + tid, xn);  // x_new
        stv<T>(out, 34304 + bi*3 + tid, vn);  // v_new
    }
}

__global__ void __launch_bounds__(512, 4) k_sake(Args A,
                                                 const short* __restrict__ U1w,
                                                 const float* __restrict__ Ajw,
                                                 const short* __restrict__ wxt,
                                                 void* __restrict__ out)
{
    __shared__ Smem S;
    if (detect_f32(A.means)) sake_body<float>(A, U1w, Ajw, wxt, out, S);
    else                     sake_body<bf16 >(A, U1w, Ajw, wxt, out, S);
}

extern "C" void kernel_launch(void* const* d_in, const int* in_sizes, int n_in,
                              void* d_out, int out_size, void* d_ws, size_t ws_size,
                              hipStream_t stream)
{
    Args A;
    A.h     = d_in[0];  A.x     = d_in[1];  A.v     = d_in[2];
    A.Win   = d_in[3];  A.bin   = d_in[4];  A.means = d_in[5];  A.betas = d_in[6];
    A.Wo1   = d_in[7];  A.bo1   = d_in[8];  A.Wo2   = d_in[9];  A.bo2   = d_in[10];
    A.Wsem  = d_in[11]; A.bsem  = d_in[12]; A.Wx    = d_in[13];
    A.Wp1   = d_in[14]; A.bp1   = d_in[15]; A.Wp2   = d_in[16]; A.bp2   = d_in[17];
    A.Wn1   = d_in[18]; A.bn1   = d_in[19]; A.Wn2   = d_in[20]; A.bn2   = d_in[21];
    A.Wv1   = d_in[22]; A.bv1   = d_in[23]; A.Wv2   = d_in[24]; A.Wvm   = d_in[25];

    // ws: U1 bf16 512x64 (64KB) | Aj f32 512x64 (128KB) | wxtE bf16 4x384x64 (192KB)
    short* U1b  = (short*)d_ws;
    float* Aj   = (float*)((char*)d_ws + 65536);
    short* WxT  = (short*)((char*)d_ws + 65536 + 131072);

    k_nodepre<<<NNODE, 256, 0, stream>>>(A, U1b, Aj, WxT);
    k_sake<<<NNODE, 512, 0, stream>>>(A, U1b, Aj, WxT, d_out);
}

// Round 4
// 171.650 us; speedup vs baseline: 1.5865x; 1.5865x over previous
//
#include <hip/hip_runtime.h>
#include <hip/hip_bf16.h>

typedef __hip_bfloat16 bf16;
typedef __attribute__((ext_vector_type(8))) short bf16x8;
typedef __attribute__((ext_vector_type(4))) short s16x4;
typedef __attribute__((ext_vector_type(4))) float f32x4;

#define NNODE 512   // B*N

__device__ __forceinline__ float b2f(bf16 v){ return __bfloat162float(v); }
__device__ __forceinline__ float siluf(float x){ return x / (1.f + __expf(-x)); }
__device__ __forceinline__ float tanhfast(float x){ return 1.f - 2.f/(__expf(2.f*x)+1.f); }
__device__ __forceinline__ float celu2(float x){ return x > 0.f ? x : 2.f*(__expf(0.5f*x)-1.f); }
__device__ __forceinline__ float bs2f(short v){ union{unsigned int i; float f;} t; t.i = ((unsigned int)(unsigned short)v) << 16; return t.f; }
__device__ __forceinline__ short f2bs(float x){ union{ bf16 b; short s; } u; u.b = __float2bfloat16(x); return u.s; }
__device__ __forceinline__ float lo16f(unsigned int u){ union{unsigned int i; float f;} t; t.i = u<<16; return t.f; }
__device__ __forceinline__ float hi16f(unsigned int u){ union{unsigned int i; float f;} t; t.i = u & 0xffff0000u; return t.f; }

// ---- dtype-polymorphic scalar load/store -------------------------------------------
template<typename T> __device__ __forceinline__ float ldv(const void* p, int i);
template<> __device__ __forceinline__ float ldv<float>(const void* p, int i){ return ((const float*)p)[i]; }
template<> __device__ __forceinline__ float ldv<bf16 >(const void* p, int i){ return b2f(((const bf16*)p)[i]); }

template<typename T> __device__ __forceinline__ void stv(void* p, int i, float v);
template<> __device__ __forceinline__ void stv<float>(void* p, int i, float v){ ((float*)p)[i] = v; }
template<> __device__ __forceinline__ void stv<bf16 >(void* p, int i, float v){ ((bf16*)p)[i] = __float2bfloat16(v); }

template<typename T> __device__ __forceinline__ short ldbs(const void* p, int i);
template<> __device__ __forceinline__ short ldbs<bf16 >(const void* p, int i){ union{ bf16 b; short s; } u; u.b = ((const bf16*)p)[i]; return u.s; }
template<> __device__ __forceinline__ short ldbs<float>(const void* p, int i){ return f2bs(((const float*)p)[i]); }

struct Args {
    const void *h,*x,*v,*Win,*bin,*means,*betas,*Wo1,*bo1,*Wo2,*bo2,*Wsem,*bsem,*Wx,
               *Wp1,*bp1,*Wp2,*bp2,*Wn1,*bn1,*Wn2,*bn2,*Wv1,*bv1,*Wv2,*Wvm;
};

__device__ __forceinline__ bool detect_f32(const void* means){
    float v = b2f(((const bf16*)means)[0]);
    return (fabsf(v) > 1.0f || v != v);
}

// ---- per-node precompute (R2 version: wxt = [h][256][64] Wx transpose only) --------
template<typename T>
__device__ __forceinline__ void nodepre_body(const Args& A, short* __restrict__ U1,
                                             float* __restrict__ Aj, short* __restrict__ WxT,
                                             float* sh, float (*p1)[64], float (*p2)[64])
{
    int bn = blockIdx.x, tid = threadIdx.x;
    int t = tid & 63, ks = tid >> 6;
    if (tid < 64) sh[tid] = ldv<T>(A.h, bn*64 + tid);
    __syncthreads();
    float a1 = 0.f;
    #pragma unroll
    for (int q = 0; q < 16; ++q){
        int f = ks*16 + q;
        a1 += sh[f] * ldv<T>(A.Wo1, f*64 + t);
    }
    p1[ks][t] = a1;
    if (t < 50){
        float a2 = 0.f;
        #pragma unroll
        for (int q = 0; q < 16; ++q){
            int f = ks*16 + q;
            a2 += sh[f] * ldv<T>(A.Win, f*50 + t);
        }
        p2[ks][t] = a2;
    }
    if (tid < 128){
        int oo = bn*128 + tid;
        int hh = oo >> 14, rem = oo & 16383, n = rem >> 6, f = oo & 63;
        WxT[oo] = ldbs<T>(A.Wx, (4*f + hh)*256 + n);
    }
    __syncthreads();
    if (tid < 64){
        U1[bn*64 + tid] = f2bs(p1[0][tid] + p1[1][tid] + p1[2][tid] + p1[3][tid]);
        float av = (tid < 50) ? (p2[0][tid] + p2[1][tid] + p2[2][tid] + p2[3][tid]) : 0.f;
        Aj[bn*64 + tid] = av;
    }
}

__global__ void __launch_bounds__(256) k_nodepre(Args A, short* __restrict__ U1,
                                                 float* __restrict__ Aj, short* __restrict__ WxT)
{
    __shared__ float sh[64];
    __shared__ float p1[4][64];
    __shared__ float p2[4][64];
    if (detect_f32(A.means)) nodepre_body<float>(A, U1, Aj, WxT, sh, p1, p2);
    else                     nodepre_body<bf16 >(A, U1, Aj, WxT, sh, p1, p2);
}

// ---- fused SAKE layer: one block per node, 512 threads (8 waves) ------------------
// R4 = R2 structure (84us, no spill) + register-cheap barrier cuts from R3:
//   single-barrier stage; logits fused into edge (same-wave rows, att in e-padding);
//   cn||dv overlap; split-N shfl tail GEMVs. he-fold MFMA and nf2-outer xmix (R3's
//   spill sources) NOT taken. Barriers ~19 -> ~13.
struct SmemPost {
    float part[4][256];                // h_e j-split partials      4096
    float red[768];                    // comb_sum                  3072
    float cn[256];                     // comb_norm                 1024
    float he[256];                     // h_e                       1024
    float fa[64];                      // f1/f3                      256
    float fb[64];                      // f2/f4                      256
    float tmp[8][4];                   // softmax max/sum, dv        128
    float tmp2[8];                     // vscale partials             32
};                                     // 9888
struct Smem {
    __align__(16) bf16  e[256][72];    // cols 0..63 e; shorts 64..71 = att[j][4] f32
    __align__(16) float x4[256][4];    // xhat[3], d                 4096
    float hi[64];                      //                             256
    float ub[64];                      // u2 + bo1                    256
    float wl[64];                      // Wo1 dist row                256
    __align__(16) float kc[64][4];     // mu, beta, bin, aiv         1024
    __align__(16) short wsem[256];     //                             512
    __align__(16) short wo1t[64*72];   // Wo1r^T [n][k pad72]        9216
    __align__(16) short wo2t[64*72];   // Wo2^T  [n][k pad72]        9216
    union {
        SmemPost post;                 // post-edge                  9888
        __align__(16) short mid[8][16][72]; // edge o1 scratch      18432
    } u;
};                                     // total 80128 -> 2 blocks/CU

__device__ __forceinline__ float* attp(Smem& S, int j){
    return (float*)((short*)S.e + j*72 + 64);
}

template<typename T>
__device__ __forceinline__ void sake_body(const Args& A,
        const short* __restrict__ U1w, const float* __restrict__ Ajw,
        const short* __restrict__ wxt, void* __restrict__ out, Smem& S)
{
    int bi = blockIdx.x;
    int b = bi >> 8, i = bi & 255;
    int tid = threadIdx.x, w = tid >> 6, lane = tid & 63;
    int lane15 = lane & 15, quad = lane >> 4;

    // ---- stage (single phase; u2/aiv read h from GLOBAL, not LDS) -----------------
    if (tid < 64)  S.hi[tid]   = ldv<T>(A.h, bi*64 + tid);
    if (tid < 256) S.wsem[tid] = ldbs<T>(A.Wsem, tid);
    if (tid < 64){
        bool kv = tid < 50;
        S.kc[tid][0] = kv ? ldv<T>(A.means, tid) : 0.f;
        S.kc[tid][1] = kv ? ldv<T>(A.betas, tid) : 0.f;
        S.kc[tid][2] = kv ? ldv<T>(A.bin,   tid) : 0.f;
        if (!kv) S.kc[tid][3] = 0.f;
    }
    #pragma unroll
    for (int q = 0; q < 8; ++q){
        int idx = q*512 + tid;                // 0..4095
        int n = idx >> 6, k = idx & 63;
        S.wo2t[n*72 + k] = ldbs<T>(A.Wo2, k*64 + n);
        S.wo1t[n*72 + k] = (k < 50) ? ldbs<T>(A.Wo1, (128+k)*64 + n) : (short)0;
    }
    float xi0 = ldv<T>(A.x, bi*3+0), xi1 = ldv<T>(A.x, bi*3+1), xi2 = ldv<T>(A.x, bi*3+2);
    if (tid < 256){
        int j = tid;
        float dx = ldv<T>(A.x,(b*256+j)*3+0) - xi0;
        float dy = ldv<T>(A.x,(b*256+j)*3+1) - xi1;
        float dz = ldv<T>(A.x,(b*256+j)*3+2) - xi2;
        float dd = sqrtf(dx*dx + dy*dy + dz*dz + 1e-5f);
        float inv = 1.f/(dd + 1e-5f);
        S.x4[j][0] = dx*inv; S.x4[j][1] = dy*inv; S.x4[j][2] = dz*inv; S.x4[j][3] = dd;
    }
    if (w == 0){
        float u2v = 0.f;
        for (int f = 0; f < 64; ++f) u2v += ldv<T>(A.h, bi*64 + f) * ldv<T>(A.Wo1, (64+f)*64 + lane);
        S.ub[lane] = u2v + ldv<T>(A.bo1, lane);
        S.wl[lane] = ldv<T>(A.Wo1, 178*64 + lane);
    } else if (w == 1 && lane < 50){
        float av = 0.f;
        for (int f = 0; f < 64; ++f) av += ldv<T>(A.h, bi*64 + f) * ldv<T>(A.Win, (64+f)*50 + lane);
        S.kc[lane][3] = av;
    }
    __syncthreads();   // everything staged

    // per-lane hoisted C-init constants: rows m = nf*16 + quad*4 + r
    float ubr[16], wlr[16], bo2r[16];
    #pragma unroll
    for (int nf = 0; nf < 4; ++nf){
        #pragma unroll
        for (int r = 0; r < 4; ++r){
            int m = nf*16 + quad*4 + r;
            ubr[nf*4+r]  = S.ub[m];
            wlr[nf*4+r]  = S.wl[m];
            bo2r[nf*4+r] = ldv<T>(A.bo2, m);
        }
    }

    // ================= edge phase: 2 passes x (8 waves x 16 pairs) =================
    for (int pass = 0; pass < 2; ++pass){
        int j = pass*128 + w*16 + lane15;     // this lane's pair
        float dd  = S.x4[j][3];
        float cut = (dd < 5.f) ? 0.5f*(__cosf(dd*0.6283185307f) + 1.f) : 0.f;
        float ed  = __expf(-dd);
        const float* ajp = Ajw + (b*256 + j)*64;
        bf16x8 Brb[2];
        #pragma unroll
        for (int s = 0; s < 2; ++s){
            int kb = s*32 + quad*8;
            f32x4 a0 = *(const f32x4*)(ajp + kb);
            f32x4 a1 = *(const f32x4*)(ajp + kb + 4);
            bf16x8 bv;
            #pragma unroll
            for (int i2 = 0; i2 < 8; ++i2){
                int k = kb + i2;
                f32x4 kcv = *(const f32x4*)&S.kc[k][0];   // mu, beta, bin, aiv
                float aj = (i2 < 4) ? a0[i2] : a1[i2-4];
                float h1 = aj + kcv[3] + kcv[2];
                float ex = ed - kcv[0];
                float val = cut * __expf(-kcv[1]*ex*ex) * h1;
                bv[i2] = (k < 50) ? f2bs(val) : (short)0;
            }
            Brb[s] = bv;
        }
        const short* u1p = U1w + (b*256 + j)*64;
        #pragma unroll
        for (int nf = 0; nf < 4; ++nf){
            const short* wp = S.wo1t + (nf*16 + lane15)*72;
            bf16x8 A0 = *(const bf16x8*)(wp + quad*8);
            bf16x8 A1 = *(const bf16x8*)(wp + 32 + quad*8);
            s16x4 u4 = *(const s16x4*)(u1p + nf*16 + quad*4);
            f32x4 C;
            #pragma unroll
            for (int r = 0; r < 4; ++r)
                C[r] = bs2f(u4[r]) + ubr[nf*4+r] + dd*wlr[nf*4+r];
            C = __builtin_amdgcn_mfma_f32_16x16x32_bf16(A0, Brb[0], C, 0, 0, 0);
            C = __builtin_amdgcn_mfma_f32_16x16x32_bf16(A1, Brb[1], C, 0, 0, 0);
            s16x4 m4;
            #pragma unroll
            for (int r = 0; r < 4; ++r) m4[r] = f2bs(siluf(C[r]));
            *(s16x4*)&S.u.mid[w][lane15][nf*16 + quad*4] = m4;
        }
        bf16x8 Bm0 = *(const bf16x8*)&S.u.mid[w][lane15][quad*8];
        bf16x8 Bm1 = *(const bf16x8*)&S.u.mid[w][lane15][32 + quad*8];
        #pragma unroll
        for (int nf = 0; nf < 4; ++nf){
            const short* wp = S.wo2t + (nf*16 + lane15)*72;
            bf16x8 A0 = *(const bf16x8*)(wp + quad*8);
            bf16x8 A1 = *(const bf16x8*)(wp + 32 + quad*8);
            f32x4 C = (f32x4){bo2r[nf*4+0], bo2r[nf*4+1], bo2r[nf*4+2], bo2r[nf*4+3]};
            C = __builtin_amdgcn_mfma_f32_16x16x32_bf16(A0, Bm0, C, 0, 0, 0);
            C = __builtin_amdgcn_mfma_f32_16x16x32_bf16(A1, Bm1, C, 0, 0, 0);
            s16x4 e4;
            #pragma unroll
            for (int r = 0; r < 4; ++r) e4[r] = f2bs(C[r]);
            *(s16x4*)&((short*)S.e)[j*72 + nf*16 + quad*4] = e4;
        }
    }

    // ===== logits fused into edge (tiles {w, 8+w} = rows THIS wave just wrote) =====
    {
        bf16x8 Bs[2];
        #pragma unroll
        for (int ks = 0; ks < 2; ++ks){
            bf16x8 bv = (bf16x8){0,0,0,0,0,0,0,0};
            if (lane15 < 4){
                #pragma unroll
                for (int i2 = 0; i2 < 8; ++i2)
                    bv[i2] = S.wsem[(ks*32 + quad*8 + i2)*4 + lane15];
            }
            Bs[ks] = bv;
        }
        float bsv = (lane15 < 4) ? ldv<T>(A.bsem, lane15) : 0.f;
        #pragma unroll
        for (int t2 = 0; t2 < 2; ++t2){
            int jt = t2 ? (8 + w) : w;
            const short* ep = (const short*)S.e + (jt*16 + lane15)*72;
            bf16x8 A0 = *(const bf16x8*)(ep + quad*8);
            bf16x8 A1 = *(const bf16x8*)(ep + 32 + quad*8);
            f32x4 C = (f32x4){bsv, bsv, bsv, bsv};
            C = __builtin_amdgcn_mfma_f32_16x16x32_bf16(A0, Bs[0], C, 0, 0, 0);
            C = __builtin_amdgcn_mfma_f32_16x16x32_bf16(A1, Bs[1], C, 0, 0, 0);
            if (lane15 < 4){
                #pragma unroll
                for (int r = 0; r < 4; ++r){
                    int jr = jt*16 + quad*4 + r;
                    float lv = celu2(C[r]);
                    if (jr == i) lv -= 1e5f;
                    attp(S, jr)[lane15] = lv;
                }
            }
        }
    }
    __syncthreads();   // e + logits visible

    // ================= softmax over j (4 heads; shfl + 8-wave combine) =============
    float ex0 = 0.f, ex1 = 0.f, ex2 = 0.f, ex3 = 0.f;
    if (tid < 256){
        f32x4 l = *(const f32x4*)attp(S, tid);
        float m0 = l[0], m1 = l[1], m2 = l[2], m3 = l[3];
        #pragma unroll
        for (int off = 1; off < 64; off <<= 1){
            m0 = fmaxf(m0, __shfl_xor(m0, off)); m1 = fmaxf(m1, __shfl_xor(m1, off));
            m2 = fmaxf(m2, __shfl_xor(m2, off)); m3 = fmaxf(m3, __shfl_xor(m3, off));
        }
        if (lane == 0){
            S.u.post.tmp[w][0] = m0; S.u.post.tmp[w][1] = m1;
            S.u.post.tmp[w][2] = m2; S.u.post.tmp[w][3] = m3;
        }
        ex0 = l[0]; ex1 = l[1]; ex2 = l[2]; ex3 = l[3];
    }
    __syncthreads();
    if (tid < 256){
        float m0 = fmaxf(fmaxf(S.u.post.tmp[0][0], S.u.post.tmp[1][0]), fmaxf(S.u.post.tmp[2][0], S.u.post.tmp[3][0]));
        float m1 = fmaxf(fmaxf(S.u.post.tmp[0][1], S.u.post.tmp[1][1]), fmaxf(S.u.post.tmp[2][1], S.u.post.tmp[3][1]));
        float m2 = fmaxf(fmaxf(S.u.post.tmp[0][2], S.u.post.tmp[1][2]), fmaxf(S.u.post.tmp[2][2], S.u.post.tmp[3][2]));
        float m3 = fmaxf(fmaxf(S.u.post.tmp[0][3], S.u.post.tmp[1][3]), fmaxf(S.u.post.tmp[2][3], S.u.post.tmp[3][3]));
        ex0 = __expf(ex0-m0); ex1 = __expf(ex1-m1); ex2 = __expf(ex2-m2); ex3 = __expf(ex3-m3);
        float s0 = ex0, s1 = ex1, s2 = ex2, s3 = ex3;
        #pragma unroll
        for (int off = 1; off < 64; off <<= 1){
            s0 += __shfl_xor(s0, off); s1 += __shfl_xor(s1, off);
            s2 += __shfl_xor(s2, off); s3 += __shfl_xor(s3, off);
        }
        if (lane == 0){
            S.u.post.tmp[4+w][0] = s0; S.u.post.tmp[4+w][1] = s1;
            S.u.post.tmp[4+w][2] = s2; S.u.post.tmp[4+w][3] = s3;
        }
    }
    __syncthreads();
    if (tid < 256){
        float s0 = S.u.post.tmp[4][0]+S.u.post.tmp[5][0]+S.u.post.tmp[6][0]+S.u.post.tmp[7][0];
        float s1 = S.u.post.tmp[4][1]+S.u.post.tmp[5][1]+S.u.post.tmp[6][1]+S.u.post.tmp[7][1];
        float s2 = S.u.post.tmp[4][2]+S.u.post.tmp[5][2]+S.u.post.tmp[6][2]+S.u.post.tmp[7][2];
        float s3 = S.u.post.tmp[4][3]+S.u.post.tmp[5][3]+S.u.post.tmp[6][3]+S.u.post.tmp[7][3];
        *(f32x4*)attp(S, tid) = (f32x4){ex0/s0, ex1/s1, ex2/s2, ex3/s3};
    }
    __syncthreads();

    // ================= h_e: dword-packed e reads, 4-way j-split ====================
    {
        int cg = tid & 127, js = tid >> 7;
        int fp = cg >> 2, hh = cg & 3;
        float acc0 = 0.f, acc1 = 0.f;
        const unsigned int* ep = (const unsigned int*)S.e;   // row stride 36 dwords
        for (int jj = 0; jj < 64; ++jj){
            int j = js*64 + jj;
            unsigned int u = ep[j*36 + fp];
            float a = attp(S, j)[hh];
            acc0 += lo16f(u)*a; acc1 += hi16f(u)*a;
        }
        S.u.post.part[js][8*fp + hh]     = acc0;
        S.u.post.part[js][8*fp + 4 + hh] = acc1;
    }
    __syncthreads();
    if (tid < 256)
        S.u.post.he[tid] = S.u.post.part[0][tid] + S.u.post.part[1][tid]
                         + S.u.post.part[2][tid] + S.u.post.part[3][tid];

    // ================= x-mixing: mt-fused att-factored MFMA (R2 structure) =========
    {
        const short* se_s = (const short*)S.e;   // row stride 72 shorts
        bf16x8 Bh[2][4][2];                      // [nf2][h][ks]
        #pragma unroll
        for (int nf2 = 0; nf2 < 2; ++nf2){
            int n = w*32 + nf2*16 + lane15;
            #pragma unroll
            for (int hh = 0; hh < 4; ++hh){
                const short* bp = wxt + (hh*256 + n)*64 + quad*8;
                Bh[nf2][hh][0] = *(const bf16x8*)(bp);
                Bh[nf2][hh][1] = *(const bf16x8*)(bp + 32);
            }
        }
        float ca[2][3];
        #pragma unroll
        for (int nf2 = 0; nf2 < 2; ++nf2){ ca[nf2][0]=0.f; ca[nf2][1]=0.f; ca[nf2][2]=0.f; }

        for (int mt = 0; mt < 16; ++mt){
            int jq = mt*16 + quad*4;
            f32x4 att4[4];
            #pragma unroll
            for (int r = 0; r < 4; ++r) att4[r] = *(const f32x4*)attp(S, jq + r);
            bf16x8 Af[2];
            #pragma unroll
            for (int ks = 0; ks < 2; ++ks)
                Af[ks] = *(const bf16x8*)(se_s + (mt*16 + lane15)*72 + ks*32 + quad*8);
            #pragma unroll
            for (int nf2 = 0; nf2 < 2; ++nf2){
                float Pt[4] = {0.f, 0.f, 0.f, 0.f};
                #pragma unroll
                for (int hh = 0; hh < 4; ++hh){
                    f32x4 Cc = (f32x4){0.f,0.f,0.f,0.f};
                    Cc = __builtin_amdgcn_mfma_f32_16x16x32_bf16(Af[0], Bh[nf2][hh][0], Cc, 0, 0, 0);
                    Cc = __builtin_amdgcn_mfma_f32_16x16x32_bf16(Af[1], Bh[nf2][hh][1], Cc, 0, 0, 0);
                    #pragma unroll
                    for (int r = 0; r < 4; ++r) Pt[r] += att4[r][hh] * Cc[r];
                }
                #pragma unroll
                for (int r = 0; r < 4; ++r){
                    float cf = tanhfast(Pt[r]);
                    f32x4 xh = *(const f32x4*)&S.x4[jq + r][0];
                    ca[nf2][0] += cf*xh[0]; ca[nf2][1] += cf*xh[1]; ca[nf2][2] += cf*xh[2];
                }
            }
        }
        #pragma unroll
        for (int nf2 = 0; nf2 < 2; ++nf2){
            #pragma unroll
            for (int d = 0; d < 3; ++d){
                float vs = ca[nf2][d];
                vs += __shfl_xor(vs, 16);
                vs += __shfl_xor(vs, 32);
                if (quad == 0) S.u.post.red[(w*32 + nf2*16 + lane15)*3 + d] = vs;
            }
        }
    }
    __syncthreads();

    // ================= cn (waves 0-3) | dv partials (waves 4-7) ====================
    const float sc = 1.f/256.f;
    if (tid < 256){
        float c0 = S.u.post.red[tid*3+0]*sc, c1 = S.u.post.red[tid*3+1]*sc, c2 = S.u.post.red[tid*3+2]*sc;
        S.u.post.cn[tid] = c0*c0 + c1*c1 + c2*c2;
    } else {
        int c = (w-4)*64 + lane;
        float wv = ldv<T>(A.Wvm, c);
        float d0 = S.u.post.red[c*3+0]*sc*wv;
        float d1 = S.u.post.red[c*3+1]*sc*wv;
        float d2 = S.u.post.red[c*3+2]*sc*wv;
        #pragma unroll
        for (int off = 1; off < 64; off <<= 1){
            d0 += __shfl_xor(d0, off); d1 += __shfl_xor(d1, off); d2 += __shfl_xor(d2, off);
        }
        if (lane == 0){ S.u.post.tmp[w-4][0] = d0; S.u.post.tmp[w-4][1] = d1; S.u.post.tmp[w-4][2] = d2; }
    }
    __syncthreads();

    int fs = lane & 7, ks8 = lane >> 3;
    int fo = w*8 + fs;
    // p1: K=256 split 8 ways over lane groups
    {
        float acc = 0.f;
        int c0 = ks8*32;
        for (int it = 0; it < 32; ++it){
            int c = c0 + it;
            acc += S.u.post.cn[c] * ldv<T>(A.Wp1, c*64 + fo);
        }
        acc += __shfl_xor(acc, 8); acc += __shfl_xor(acc, 16); acc += __shfl_xor(acc, 32);
        if (lane < 8) S.u.post.fa[w*8 + lane] = siluf(acc + ldv<T>(A.bp1, w*8 + lane));
    }
    __syncthreads();
    // p2: K=64
    {
        float acc = 0.f;
        #pragma unroll
        for (int q = 0; q < 8; ++q){
            int k = ks8*8 + q;
            acc += S.u.post.fa[k] * ldv<T>(A.Wp2, k*64 + fo);
        }
        acc += __shfl_xor(acc, 8); acc += __shfl_xor(acc, 16); acc += __shfl_xor(acc, 32);
        if (lane < 8) S.u.post.fb[w*8 + lane] = siluf(acc + ldv<T>(A.bp2, w*8 + lane));
    }
    __syncthreads();
    // n1: K=384 (64 h | 256 h_e | 64 f2), 48 rows per lane group
    {
        float acc = 0.f;
        int r0 = ks8*48;
        for (int it = 0; it < 48; ++it){
            int r = r0 + it;
            float xv = (r < 64) ? S.hi[r] : (r < 320) ? S.u.post.he[r-64] : S.u.post.fb[r-320];
            acc += xv * ldv<T>(A.Wn1, r*64 + fo);
        }
        acc += __shfl_xor(acc, 8); acc += __shfl_xor(acc, 16); acc += __shfl_xor(acc, 32);
        if (lane < 8){
            int f = w*8 + lane;
            S.u.post.fa[f] = siluf(acc + ldv<T>(A.bn1, f));   // f3
        }
    }
    __syncthreads();
    // n2: K=64 -> h_new
    {
        float acc = 0.f;
        #pragma unroll
        for (int q = 0; q < 8; ++q){
            int k = ks8*8 + q;
            acc += S.u.post.fa[k] * ldv<T>(A.Wn2, k*64 + fo);
        }
        acc += __shfl_xor(acc, 8); acc += __shfl_xor(acc, 16); acc += __shfl_xor(acc, 32);
        if (lane < 8){
            int f = w*8 + lane;
            float hn = S.hi[f] + siluf(acc + ldv<T>(A.bn2, f));
            stv<T>(out, bi*64 + f, hn);
            S.u.post.fb[f] = hn;             // f4 = h_new
        }
    }
    __syncthreads();
    // v1: K=64 -> per-wave term partials
    {
        float acc = 0.f;
        #pragma unroll
        for (int q = 0; q < 8; ++q){
            int k = ks8*8 + q;
            acc += S.u.post.fb[k] * ldv<T>(A.Wv1, k*64 + fo);
        }
        acc += __shfl_xor(acc, 8); acc += __shfl_xor(acc, 16); acc += __shfl_xor(acc, 32);
        float term = siluf(acc + ldv<T>(A.bv1, fo)) * ldv<T>(A.Wv2, fo);
        term += __shfl_xor(term, 1); term += __shfl_xor(term, 2); term += __shfl_xor(term, 4);
        if (lane == 0) S.u.post.tmp2[w] = term;
    }
    __syncthreads();
    if (tid < 3){
        float t = S.u.post.tmp2[0]+S.u.post.tmp2[1]+S.u.post.tmp2[2]+S.u.post.tmp2[3]
                + S.u.post.tmp2[4]+S.u.post.tmp2[5]+S.u.post.tmp2[6]+S.u.post.tmp2[7];
        float vscale = 2.f / (1.f + __expf(-t));
        float dv = S.u.post.tmp[0][tid] + S.u.post.tmp[1][tid] + S.u.post.tmp[2][tid] + S.u.post.tmp[3][tid];
        float vn = dv + vscale * ldv<T>(A.v, bi*3 + tid);
        float xn = ldv<T>(A.x, bi*3 + tid) + vn;
        stv<T>(out, 32768 + bi*3 + tid, xn);  // x_new
        stv<T>(out, 34304 + bi*3 + tid, vn);  // v_new
    }
}

__global__ void __launch_bounds__(512, 4) k_sake(Args A,
                                                 const short* __restrict__ U1w,
                                                 const float* __restrict__ Ajw,
                                                 const short* __restrict__ wxt,
                                                 void* __restrict__ out)
{
    __shared__ Smem S;
    if (detect_f32(A.means)) sake_body<float>(A, U1w, Ajw, wxt, out, S);
    else                     sake_body<bf16 >(A, U1w, Ajw, wxt, out, S);
}

extern "C" void kernel_launch(void* const* d_in, const int* in_sizes, int n_in,
                              void* d_out, int out_size, void* d_ws, size_t ws_size,
                              hipStream_t stream)
{
    Args A;
    A.h     = d_in[0];  A.x     = d_in[1];  A.v     = d_in[2];
    A.Win   = d_in[3];  A.bin   = d_in[4];  A.means = d_in[5];  A.betas = d_in[6];
    A.Wo1   = d_in[7];  A.bo1   = d_in[8];  A.Wo2   = d_in[9];  A.bo2   = d_in[10];
    A.Wsem  = d_in[11]; A.bsem  = d_in[12]; A.Wx    = d_in[13];
    A.Wp1   = d_in[14]; A.bp1   = d_in[15]; A.Wp2   = d_in[16]; A.bp2   = d_in[17];
    A.Wn1   = d_in[18]; A.bn1   = d_in[19]; A.Wn2   = d_in[20]; A.bn2   = d_in[21];
    A.Wv1   = d_in[22]; A.bv1   = d_in[23]; A.Wv2   = d_in[24]; A.Wvm   = d_in[25];

    // ws layout: U1 bf16 512x64 (64KB) | Aj f32 512x64 (128KB) | WxH bf16 4x256x64 (128KB)
    short* U1b  = (short*)d_ws;
    float* Aj   = (float*)((char*)d_ws + 65536);
    short* WxT  = (short*)((char*)d_ws + 65536 + 131072);

    k_nodepre<<<NNODE, 256, 0, stream>>>(A, U1b, Aj, WxT);
    k_sake<<<NNODE, 512, 0, stream>>>(A, U1b, Aj, WxT, d_out);
}